// Round 6
// baseline (953.455 us; speedup 1.0000x reference)
//
#include <hip/hip_runtime.h>
#include <stdint.h>

// Problem constants (B=1 throughout)
static constexpr int SEQ = 4096;   // seq_len
static constexpr int HD  = 2048;   // hidden
static constexpr int CD  = 1024;   // compressed
static constexpr int KFI = 8;      // keyframe interval

typedef __bf16 bf16x8 __attribute__((ext_vector_type(8)));
typedef float  f32x4  __attribute__((ext_vector_type(4)));

__device__ __forceinline__ short f2bf(float x) {   // RNE float->bf16 bits
  union { float f; unsigned u; } v; v.f = x;
  unsigned r = v.u + 0x7fffu + ((v.u >> 16) & 1u);
  return (short)(r >> 16);
}
__device__ __forceinline__ float bf2f(short h) {
  union { unsigned u; float f; } v; v.u = ((unsigned)(unsigned short)h) << 16;
  return v.f;
}

// async global->LDS, 16B per lane. LDS dest must be wave-uniform base +
// lane*16 (linear in lane order) -- staging pattern below satisfies this.
#define GLOAD16(gp, lp) __builtin_amdgcn_global_load_lds( \
    (__attribute__((address_space(1))) void*)(gp),        \
    (__attribute__((address_space(3))) void*)(lp), 16, 0, 0)

// ---------------- prep kernels ----------------

// W [K][N] f32 row-major -> Wt [N][K] bf16 (B^T layout for the GEMM)
__global__ void transpose_cast(const float* __restrict__ W, short* __restrict__ Wt,
                               int K, int N) {
  __shared__ float tile[32][33];
  const int k0 = blockIdx.y * 32, n0 = blockIdx.x * 32;
  const int x = threadIdx.x, y = threadIdx.y;  // 32 x 8
#pragma unroll
  for (int r = 0; r < 32; r += 8)
    tile[y + r][x] = W[(size_t)(k0 + y + r) * N + n0 + x];
  __syncthreads();
#pragma unroll
  for (int r = 0; r < 32; r += 8)
    Wt[(size_t)(n0 + y + r) * K + k0 + x] = f2bf(tile[x][y + r]);
}

// selector W1 [K][N] f32 -> Wt' [N][3K] bf16 segments [hi | hi | lo]
__global__ void transpose_split(const float* __restrict__ W, short* __restrict__ Wt,
                                int K, int N) {
  __shared__ float tile[32][33];
  const int k0 = blockIdx.y * 32, n0 = blockIdx.x * 32;
  const int x = threadIdx.x, y = threadIdx.y;
#pragma unroll
  for (int r = 0; r < 32; r += 8)
    tile[y + r][x] = W[(size_t)(k0 + y + r) * N + n0 + x];
  __syncthreads();
#pragma unroll
  for (int r = 0; r < 32; r += 8) {
    float w = tile[x][y + r];
    short hi = f2bf(w);
    short lo = f2bf(w - bf2f(hi));
    size_t base = (size_t)(n0 + y + r) * (3 * K) + k0 + x;
    Wt[base]         = hi;
    Wt[base + K]     = hi;
    Wt[base + 2 * K] = lo;
  }
}

// A' [SEQ][3H] = [hi(keys_t) | lo(keys_t) | hi(keys_t)]
__global__ void build_asel(const float* __restrict__ keys, short* __restrict__ A) {
  const int t = blockIdx.y;
  const int h = blockIdx.x * 256 + threadIdx.x;
  float x = keys[(size_t)t * HD + h];
  short hi = f2bf(x);
  short lo = f2bf(x - bf2f(hi));
  size_t b = (size_t)t * (3 * HD);
  A[b + h]          = hi;
  A[b + HD + h]     = lo;
  A[b + 2 * HD + h] = hi;
}

// logits + keyframe decision + blend factor (1 wave per row)
__global__ void sel_logits(const float* __restrict__ hid, const float* __restrict__ W2,
                           const float* __restrict__ b2, const float* __restrict__ imp,
                           const int* __restrict__ fc, int* __restrict__ iskf,
                           float* __restrict__ blend) {
  const int wave = threadIdx.x >> 6, lane = threadIdx.x & 63;
  const int t = blockIdx.x * 4 + wave;
  const float* hrow = hid + (size_t)t * CD;
  float s = 0.f;
#pragma unroll
  for (int i = 0; i < CD / 64; ++i) s += hrow[lane + i * 64] * W2[lane + i * 64];
#pragma unroll
  for (int off = 32; off; off >>= 1) s += __shfl_xor(s, off);
  if (lane == 0) {
    float logit = s + b2[0];
    float score = 1.f / (1.f + expf(-logit));
    int interval = (fc[0] % KFI) == 0;
    iskf[t]  = interval || (score > 0.2f);
    blend[t] = 1.f / (1.f + expf(-5.f * imp[t]));
  }
}

// last_kf[t] = max{ j < t : iskf[j] }, else -1.  One block, 1024 thr x 4 elems.
__global__ void kf_scan(const int* __restrict__ iskf, int* __restrict__ lastkf) {
  __shared__ int part[1024];
  const int tid = threadIdx.x;
  const int base = tid * 4;
  int v[4];
  int mx = -1;
#pragma unroll
  for (int i = 0; i < 4; ++i) {
    v[i] = iskf[base + i] ? (base + i) : -1;
    mx = max(mx, v[i]);
  }
  part[tid] = mx;
  __syncthreads();
  int mine = mx;
  for (int off = 1; off < 1024; off <<= 1) {
    int other = (tid >= off) ? part[tid - off] : -1;
    __syncthreads();
    mine = max(mine, other);
    part[tid] = mine;
    __syncthreads();
  }
  int run = (tid > 0) ? part[tid - 1] : -1;   // exclusive prefix over chunks
#pragma unroll
  for (int i = 0; i < 4; ++i) {
    lastkf[base + i] = run;
    run = max(run, v[i]);
  }
}

// Xk/Xv [SEQ][2H] bf16 = [cur | prev(last_kf)]
__global__ void build_x(const float* __restrict__ keys, const float* __restrict__ vals,
                        const int* __restrict__ lastkf,
                        short* __restrict__ Xk, short* __restrict__ Xv) {
  const int t = blockIdx.y;
  const int h = blockIdx.x * 256 + threadIdx.x;
  const int lk = lastkf[t];
  const size_t cidx = (size_t)t * HD + h;
  const size_t xb = (size_t)t * (2 * HD);
  Xk[xb + h] = f2bf(keys[cidx]);
  Xv[xb + h] = f2bf(vals[cidx]);
  float pk = 0.f, pv = 0.f;
  if (lk >= 0) {
    pk = keys[(size_t)lk * HD + h];
    pv = vals[(size_t)lk * HD + h];
  }
  Xk[xb + HD + h] = f2bf(pk);
  Xv[xb + HD + h] = f2bf(pv);
}

// ---------------- MFMA GEMM (m97 structure: 128x128 tile, BK=64) ----------------
// C[M][N] = epi(A[M][K] @ Bt[N][K]^T + bias)
// EPI 0: bf16 relu -> oB          EPI 1: f32 relu -> oF
// EPI 2: pred/residual (motion)   EPI 3: final output (dec + keyframe/blend)
// NOTE: oF/predp may alias (EPI3 reads predp then overwrites the same address
// in-thread) -- so no __restrict__ on them.
template <int EPI>
__global__ __launch_bounds__(256, 2)
void gemm_bt(const short* __restrict__ A, const short* __restrict__ Bt,
             const float* __restrict__ bias, int M, int N, int K,
             short* oB, float* oF,
             const float* __restrict__ curK, const float* __restrict__ curV,
             const float* predp, const int* __restrict__ lastkf,
             const int* __restrict__ iskf, const float* __restrict__ blendp) {
  __shared__ short ldsA[128 * 64];
  __shared__ short ldsB[128 * 64];
  const int tid  = threadIdx.x;
  const int lane = tid & 63;
  const int wave = tid >> 6;
  const int wr = wave >> 1, wc = wave & 1;       // 2x2 waves, 64x64 out each
  const int bm = blockIdx.y * 128, bn = blockIdx.x * 128;
  const int lr = tid >> 3;                        // staging row 0..31
  const int lc = (tid & 7) << 3;                  // staging col (8 bf16 = 16B)

  const short* Ab = A  + (size_t)bm * K;
  const short* Bb = Bt + (size_t)bn * K;

  f32x4 acc[4][4];
#pragma unroll
  for (int m = 0; m < 4; ++m)
#pragma unroll
    for (int n = 0; n < 4; ++n) acc[m][n] = (f32x4){0.f, 0.f, 0.f, 0.f};

  const int rsel = lane & 15;           // A row / B col within fragment
  const int ksel = (lane >> 4) << 3;    // k-subgroup: 8 contiguous k per lane

  for (int k0 = 0; k0 < K; k0 += 64) {
#pragma unroll
    for (int i = 0; i < 4; ++i) {
      const int row = i * 32 + lr;
      GLOAD16(Ab + (size_t)row * K + (k0 + lc), &ldsA[row * 64 + lc]);
      GLOAD16(Bb + (size_t)row * K + (k0 + lc), &ldsB[row * 64 + lc]);
    }
    __syncthreads();
#pragma unroll
    for (int kk = 0; kk < 64; kk += 32) {
      bf16x8 af[4], bg[4];
#pragma unroll
      for (int m = 0; m < 4; ++m)
        af[m] = *(const bf16x8*)&ldsA[(wr * 64 + m * 16 + rsel) * 64 + kk + ksel];
#pragma unroll
      for (int n = 0; n < 4; ++n)
        bg[n] = *(const bf16x8*)&ldsB[(wc * 64 + n * 16 + rsel) * 64 + kk + ksel];
#pragma unroll
      for (int m = 0; m < 4; ++m)
#pragma unroll
        for (int n = 0; n < 4; ++n)
          acc[m][n] = __builtin_amdgcn_mfma_f32_16x16x32_bf16(af[m], bg[n], acc[m][n], 0, 0, 0);
    }
    __syncthreads();
  }

  // C/D layout: col = lane&15, row = (lane>>4)*4 + reg   [m89-verified]
  const int row0 = bm + wr * 64 + ((lane >> 4) << 2);
  const int col0 = bn + wc * 64 + (lane & 15);
#pragma unroll
  for (int m = 0; m < 4; ++m) {
#pragma unroll
    for (int n = 0; n < 4; ++n) {
      const int col = col0 + n * 16;
      const float bv = bias[col];
#pragma unroll
      for (int j = 0; j < 4; ++j) {
        const int row = row0 + m * 16 + j;
        float v = acc[m][n][j] + bv;
        if (EPI == 0) {
          oB[(size_t)row * N + col] = f2bf(fmaxf(v, 0.f));
        } else if (EPI == 1) {
          oF[(size_t)row * N + col] = fmaxf(v, 0.f);
        } else if (EPI == 2) {
          // v = mot[t][col]; pred = prev + mot; r = cur - pred
          const int t = row;
          const int lk = lastkf[t];
          const float prev = (lk >= 0) ? curK[(size_t)lk * HD + col] : 0.f;
          const float pred = prev + v;
          oF[(size_t)t * HD + col] = pred;
          oB[(size_t)t * HD + col] = f2bf(curK[(size_t)t * HD + col] - pred);
        } else {
          // dec epilogue: d=relu(v); rec=pred+d; keyframe select + blend
          int t = row;
          const float* cur = curK;
          float* op = oF;
          if (row >= SEQ) { t = row - SEQ; cur = curV; op = oF + (size_t)SEQ * HD; }
          const float d   = fmaxf(v, 0.f);
          const float rec = predp[(size_t)row * HD + col] + d;
          const float c   = cur[(size_t)t * HD + col];
          const float pos = iskf[t] ? c : rec;
          const float bl  = blendp[t];
          op[(size_t)t * HD + col] = bl * c + (1.f - bl) * pos;
        }
      }
    }
  }
}

static void launch_gemm(int epi, dim3 g, hipStream_t st,
                        const short* A, const short* Bt, const float* bias,
                        int M, int N, int K, short* oB, float* oF,
                        const float* curK, const float* curV, const float* predp,
                        const int* lastkf, const int* iskf, const float* blendp) {
  dim3 b(256);
  switch (epi) {
    case 0: gemm_bt<0><<<g, b, 0, st>>>(A, Bt, bias, M, N, K, oB, oF, curK, curV, predp, lastkf, iskf, blendp); break;
    case 1: gemm_bt<1><<<g, b, 0, st>>>(A, Bt, bias, M, N, K, oB, oF, curK, curV, predp, lastkf, iskf, blendp); break;
    case 2: gemm_bt<2><<<g, b, 0, st>>>(A, Bt, bias, M, N, K, oB, oF, curK, curV, predp, lastkf, iskf, blendp); break;
    default: gemm_bt<3><<<g, b, 0, st>>>(A, Bt, bias, M, N, K, oB, oF, curK, curV, predp, lastkf, iskf, blendp); break;
  }
}

extern "C" void kernel_launch(void* const* d_in, const int* in_sizes, int n_in,
                              void* d_out, int out_size, void* d_ws, size_t ws_size,
                              hipStream_t stream) {
  const float* keys  = (const float*)d_in[0];
  const float* vals  = (const float*)d_in[1];
  const float* imp   = (const float*)d_in[2];
  const float* kmW1  = (const float*)d_in[3];
  const float* kmb1  = (const float*)d_in[4];
  const float* kmW2  = (const float*)d_in[5];
  const float* kmb2  = (const float*)d_in[6];
  const float* vmW1  = (const float*)d_in[7];
  const float* vmb1  = (const float*)d_in[8];
  const float* vmW2  = (const float*)d_in[9];
  const float* vmb2  = (const float*)d_in[10];
  const float* encW  = (const float*)d_in[11];
  const float* encb  = (const float*)d_in[12];
  const float* decW  = (const float*)d_in[13];
  const float* decb  = (const float*)d_in[14];
  const float* selW1 = (const float*)d_in[15];
  const float* selb1 = (const float*)d_in[16];
  const float* selW2 = (const float*)d_in[17];
  const float* selb2 = (const float*)d_in[18];
  const int*   fc    = (const int*)d_in[19];
  float* out = (float*)d_out;

  // ---- workspace arena: 120 MiB + 48 KB (lifetime-overlapped slots) ----
  const size_t MB = 1u << 20;
  char* ws = (char*)d_ws;
  // slotW [0,56Mi): motion/autoenc weights; hidV overlays dead kmW1t
  short* kmW1t = (short*)(ws +  0 * MB);   // [2048][4096]  dead after km1
  short* hidV  = (short*)(ws +  0 * MB);   // [4096][2048]  born at vm1
  short* kmW2t = (short*)(ws + 16 * MB);   // [2048][2048]  dead after km2
  short* vmW1t = (short*)(ws + 24 * MB);   // [2048][4096]  dead after vm1
  short* vmW2t = (short*)(ws + 40 * MB);   // [2048][2048]  dead after vm2
  short* encT  = (short*)(ws + 48 * MB);   // [1024][2048]  dead after enc
  short* decT  = (short*)(ws + 52 * MB);   // [2048][1024]  dead after dec
  // slotR [56,104Mi): selT (dead after selector GEMM) -> rK | rV | eKV
  short* selT  = (short*)(ws + 56 * MB);   // [1024][6144]  12 MiB
  short* rKV   = (short*)(ws + 56 * MB);   // rK [0,16Mi) @km2, rV [16,32Mi) @vm2
  short* eKV   = (short*)(ws + 88 * MB);   // [8192][1024]  @enc
  // uni2 [104,120Mi): hidS f32 (selector hidden) -> hidK bf16
  float* hidS  = (float*)(ws + 104 * MB);  // [4096][1024] f32
  short* hidK  = (short*)(ws + 104 * MB);  // [4096][2048] bf16
  // flags [120Mi, ...)
  int*   iskf  = (int*)(ws + 120 * MB);
  int*   lkf   = (int*)(ws + 120 * MB + 16384);
  float* blend = (float*)(ws + 120 * MB + 32768);

  // ---- d_out doubles as scratch until predKV is written ----
  // Asel [0,48Mi) -> Xk|Xv [0,64Mi) -> predKV f32 [0,64Mi) -> final out
  short* Asel   = (short*)d_out;                 // [4096][6144] bf16
  short* Xk     = (short*)d_out;                 // [4096][4096] bf16
  short* Xv     = Xk + (size_t)SEQ * 2 * HD;     // [4096][4096] bf16
  float* predKV = (float*)d_out;                 // [8192][2048] f32

  dim3 tb(32, 8);
  // weight transposes f32 -> bf16 [N][K]
  transpose_cast <<<dim3(HD/32, 2*HD/32), tb, 0, stream>>>(kmW1, kmW1t, 2*HD, HD);
  transpose_cast <<<dim3(HD/32,   HD/32), tb, 0, stream>>>(kmW2, kmW2t,   HD, HD);
  transpose_cast <<<dim3(HD/32, 2*HD/32), tb, 0, stream>>>(vmW1, vmW1t, 2*HD, HD);
  transpose_cast <<<dim3(HD/32,   HD/32), tb, 0, stream>>>(vmW2, vmW2t,   HD, HD);
  transpose_cast <<<dim3(CD/32,   HD/32), tb, 0, stream>>>(encW, encT,    HD, CD);
  transpose_cast <<<dim3(HD/32,   CD/32), tb, 0, stream>>>(decW, decT,    CD, HD);
  transpose_split<<<dim3(CD/32,   HD/32), tb, 0, stream>>>(selW1, selT,   HD, CD);

  // selector: split-bf16 GEMM (K=3H) for fp32-accurate logits
  build_asel<<<dim3(HD/256, SEQ), 256, 0, stream>>>(keys, Asel);
  launch_gemm(1, dim3(CD/128, SEQ/128), stream, Asel, selT, selb1, SEQ, CD, 3*HD,
              nullptr, hidS, nullptr, nullptr, nullptr, nullptr, nullptr, nullptr);
  sel_logits<<<SEQ/4, 256, 0, stream>>>(hidS, selW2, selb2, imp, fc, iskf, blend);
  kf_scan<<<1, 1024, 0, stream>>>(iskf, lkf);

  // motion path (Xk/Xv overwrite dead Asel in d_out)
  build_x<<<dim3(HD/256, SEQ), 256, 0, stream>>>(keys, vals, lkf, Xk, Xv);
  launch_gemm(0, dim3(HD/128, SEQ/128), stream, Xk, kmW1t, kmb1, SEQ, HD, 2*HD,
              hidK, nullptr, nullptr, nullptr, nullptr, nullptr, nullptr, nullptr);
  launch_gemm(0, dim3(HD/128, SEQ/128), stream, Xv, vmW1t, vmb1, SEQ, HD, 2*HD,
              hidV, nullptr, nullptr, nullptr, nullptr, nullptr, nullptr, nullptr);
  // km2/vm2 write predKV into d_out (Xk/Xv now dead) + bf16 residuals into slotR
  launch_gemm(2, dim3(HD/128, SEQ/128), stream, hidK, kmW2t, kmb2, SEQ, HD, HD,
              rKV, predKV, keys, nullptr, nullptr, lkf, nullptr, nullptr);
  launch_gemm(2, dim3(HD/128, SEQ/128), stream, hidV, vmW2t, vmb2, SEQ, HD, HD,
              rKV + (size_t)SEQ * HD, predKV + (size_t)SEQ * HD, vals,
              nullptr, nullptr, lkf, nullptr, nullptr);

  // autoencoder on stacked residuals [k;v] (shared weights) + fused final epilogue
  launch_gemm(0, dim3(CD/128, 2*SEQ/128), stream, rKV, encT, encb, 2*SEQ, CD, HD,
              eKV, nullptr, nullptr, nullptr, nullptr, nullptr, nullptr, nullptr);
  launch_gemm(3, dim3(HD/128, 2*SEQ/128), stream, eKV, decT, decb, 2*SEQ, HD, CD,
              nullptr, out, keys, vals, predKV, lkf, iskf, blend);
}

// Round 11
// 646.367 us; speedup vs baseline: 1.4751x; 1.4751x over previous
//
#include <hip/hip_runtime.h>
#include <stdint.h>

static constexpr int SEQ = 4096;
static constexpr int HD  = 2048;
static constexpr int CD  = 1024;
static constexpr int KFI = 8;
static constexpr int CAP = 3072;   // compact-row capacity (expected NC ~650)

typedef __bf16 bf16x8 __attribute__((ext_vector_type(8)));
typedef float  f32x4  __attribute__((ext_vector_type(4)));

__device__ __forceinline__ short f2bf(float x) {
  union { float f; unsigned u; } v; v.f = x;
  unsigned r = v.u + 0x7fffu + ((v.u >> 16) & 1u);
  return (short)(r >> 16);
}
__device__ __forceinline__ float bf2f(short h) {
  union { unsigned u; float f; } v; v.u = ((unsigned)(unsigned short)h) << 16;
  return v.f;
}

#define GLOAD16(gp, lp) __builtin_amdgcn_global_load_lds( \
    (__attribute__((address_space(1))) void*)(gp),        \
    (__attribute__((address_space(3))) void*)(lp), 16, 0, 0)

// ---------------- prep kernels ----------------

__global__ void transpose_cast(const float* __restrict__ W, short* __restrict__ Wt,
                               int K, int N) {
  __shared__ float tile[32][33];
  const int k0 = blockIdx.y * 32, n0 = blockIdx.x * 32;
  const int x = threadIdx.x, y = threadIdx.y;  // 32 x 8
#pragma unroll
  for (int r = 0; r < 32; r += 8)
    tile[y + r][x] = W[(size_t)(k0 + y + r) * N + n0 + x];
  __syncthreads();
#pragma unroll
  for (int r = 0; r < 32; r += 8)
    Wt[(size_t)(n0 + y + r) * K + k0 + x] = f2bf(tile[x][y + r]);
}

// selW1 [K][N] f32 -> WhiT/WloT [N][K] bf16
__global__ void transpose_hilo(const float* __restrict__ W, short* __restrict__ Whi,
                               short* __restrict__ Wlo, int K, int N) {
  __shared__ float tile[32][33];
  const int k0 = blockIdx.y * 32, n0 = blockIdx.x * 32;
  const int x = threadIdx.x, y = threadIdx.y;
#pragma unroll
  for (int r = 0; r < 32; r += 8)
    tile[y + r][x] = W[(size_t)(k0 + y + r) * N + n0 + x];
  __syncthreads();
#pragma unroll
  for (int r = 0; r < 32; r += 8) {
    float w = tile[x][y + r];
    short hi = f2bf(w);
    size_t o = (size_t)(n0 + y + r) * K + k0 + x;
    Whi[o] = hi;
    Wlo[o] = f2bf(w - bf2f(hi));
  }
}

// keys -> Ahi,Alo ; vals -> Vhi   (bf16 [SEQ][HD])
__global__ void build_hilo(const float* __restrict__ keys, const float* __restrict__ vals,
                           short* __restrict__ Ahi, short* __restrict__ Alo,
                           short* __restrict__ Vhi) {
  const int t = blockIdx.y;
  const int h = (blockIdx.x * 256 + threadIdx.x) * 4;
  const float4 k4 = *(const float4*)&keys[(size_t)t * HD + h];
  const float4 v4 = *(const float4*)&vals[(size_t)t * HD + h];
  short4 hi, lo, vh;
  const float kf[4] = {k4.x, k4.y, k4.z, k4.w};
  const float vf[4] = {v4.x, v4.y, v4.z, v4.w};
  short* hp = (short*)&hi; short* lp = (short*)&lo; short* vp = (short*)&vh;
#pragma unroll
  for (int i = 0; i < 4; ++i) {
    short h16 = f2bf(kf[i]);
    hp[i] = h16; lp[i] = f2bf(kf[i] - bf2f(h16)); vp[i] = f2bf(vf[i]);
  }
  *(short4*)&Ahi[(size_t)t * HD + h] = hi;
  *(short4*)&Alo[(size_t)t * HD + h] = lo;
  *(short4*)&Vhi[(size_t)t * HD + h] = vh;
}

// logits from 3 partials + keyframe decision + blend (1 wave per row)
__global__ void sel_logits(const float* __restrict__ h0, const float* __restrict__ h1,
                           const float* __restrict__ h2, const float* __restrict__ b1,
                           const float* __restrict__ W2, const float* __restrict__ b2,
                           const float* __restrict__ imp, const int* __restrict__ fc,
                           int* __restrict__ iskf, float* __restrict__ blend) {
  const int wave = threadIdx.x >> 6, lane = threadIdx.x & 63;
  const int t = blockIdx.x * 4 + wave;
  const size_t rb = (size_t)t * CD;
  float s = 0.f;
#pragma unroll
  for (int i = 0; i < CD / 64; ++i) {
    const int c = lane + i * 64;
    float hv = h0[rb + c] + h1[rb + c] + h2[rb + c] + b1[c];
    s += fmaxf(hv, 0.f) * W2[c];
  }
#pragma unroll
  for (int off = 32; off; off >>= 1) s += __shfl_xor(s, off);
  if (lane == 0) {
    float logit = s + b2[0];
    float score = 1.f / (1.f + expf(-logit));
    int interval = (fc[0] % KFI) == 0;
    iskf[t]  = interval || (score > 0.2f);
    blend[t] = 1.f / (1.f + expf(-5.f * imp[t]));
  }
}

// lastkf + non-kf compaction (idx, nc) + zero-row init. One block 1024 thr.
__global__ void kf_scan(int* __restrict__ iskf, int* __restrict__ lastkf,
                        int* __restrict__ idx, int* __restrict__ ncp,
                        short* __restrict__ zrow) {
  __shared__ int part[1024];
  const int tid = threadIdx.x;
  const int base = tid * 4;
  int v[4], k[4];
  int mx = -1, cnt = 0;
#pragma unroll
  for (int i = 0; i < 4; ++i) {
    k[i] = iskf[base + i];
    v[i] = k[i] ? (base + i) : -1;
    mx = max(mx, v[i]);
    cnt += !k[i];
  }
  part[tid] = mx;
  __syncthreads();
  int mine = mx;
  for (int off = 1; off < 1024; off <<= 1) {
    int other = (tid >= off) ? part[tid - off] : -1;
    __syncthreads();
    mine = max(mine, other);
    part[tid] = mine;
    __syncthreads();
  }
  int run = (tid > 0) ? part[tid - 1] : -1;
#pragma unroll
  for (int i = 0; i < 4; ++i) {
    lastkf[base + i] = run;
    run = max(run, v[i]);
  }
  __syncthreads();
  // pass 2: compact non-kf indices
  part[tid] = cnt;
  __syncthreads();
  int csum = cnt;
  for (int off = 1; off < 1024; off <<= 1) {
    int other = (tid >= off) ? part[tid - off] : 0;
    __syncthreads();
    csum += other;
    part[tid] = csum;
    __syncthreads();
  }
  int pos = csum - cnt;  // exclusive prefix
#pragma unroll
  for (int i = 0; i < 4; ++i) {
    if (!k[i]) {
      if (pos < CAP) idx[pos] = base + i;
      else iskf[base + i] = 1;   // overflow safety net: treat as keyframe
      ++pos;
    }
  }
  if (tid == 1023) *ncp = min(csum, CAP);
  zrow[tid] = 0; zrow[tid + 1024] = 0;
}

// out = cur for keyframe rows (both planes)
__global__ void copy_kf(const float* __restrict__ keys, const float* __restrict__ vals,
                        const int* __restrict__ iskf, float* __restrict__ out) {
  const int t = blockIdx.y;
  if (!iskf[t]) return;
  const int h = (blockIdx.x * 256 + threadIdx.x) * 4;
  *(float4*)&out[(size_t)t * HD + h] = *(const float4*)&keys[(size_t)t * HD + h];
  *(float4*)&out[(size_t)(SEQ + t) * HD + h] = *(const float4*)&vals[(size_t)t * HD + h];
}

// ---------------- z-fused MFMA GEMM (128x128 tile, BK=64) ----------------
// EPI: 0=RAWF (f32 partial, no bias)  1=RELUB (bf16 relu+bias)
//      2=MOT (pred/residual + s-fold into out)  3=DEC (out += (1-bl)*relu)
// AM:  0=LIN (full rows)  1=GATHER (idx/lkf rows from Ahi/Vhi panels)  2=CLIN (compact)
template <int EPI, int AM>
__global__ __launch_bounds__(256, 2)
void gemm_z(const short* __restrict__ A0, const short* __restrict__ A1,
            const short* __restrict__ A2,
            const short* __restrict__ B0, const short* __restrict__ B1,
            const short* __restrict__ B2,
            const float* __restrict__ bias0, const float* __restrict__ bias1,
            int N, int K,
            float* oF, short* oB,
            const int* __restrict__ idx, const int* __restrict__ lkf,
            const int* __restrict__ ncp, const float* __restrict__ blend,
            const float* __restrict__ keys, const float* __restrict__ vals,
            const short* __restrict__ zrow) {
  const int z  = blockIdx.z;
  const int bm = blockIdx.y * 128, bn = blockIdx.x * 128;
  int NC = SEQ;
  if (AM != 0) { NC = *ncp; if (bm >= NC) return; }

  const short* A    = (z == 0) ? A0 : (z == 1 ? A1 : A2);
  const short* Bt   = (z == 0) ? B0 : (z == 1 ? B1 : B2);
  const float* bias = (z == 0) ? bias0 : bias1;

  __shared__ short ldsA[128 * 64];
  __shared__ short ldsB[128 * 64];
  const int tid  = threadIdx.x;
  const int lane = tid & 63;
  const int wave = tid >> 6;
  const int wr = wave >> 1, wc = wave & 1;
  const int lr = tid >> 3;
  const int lc = (tid & 7) << 3;

  // per-thread A/B row base pointers (gather hoisted out of K-loop)
  const short* abase[4];
  const short* pbase[4];
  const short* bbase[4];
#pragma unroll
  for (int i = 0; i < 4; ++i) {
    const int r = bm + i * 32 + lr;
    if (AM == 1) {
      const int t  = (r < NC) ? idx[r] : 0;
      const int lk = lkf[t];
      abase[i] = A + (size_t)t * HD;
      pbase[i] = (lk >= 0) ? (A + (size_t)lk * HD) : zrow;
    } else if (AM == 2) {
      abase[i] = A + ((size_t)z * CAP + r) * K;
    } else {
      abase[i] = A + (size_t)r * K;
    }
    bbase[i] = Bt + (size_t)(bn + i * 32 + lr) * K;
  }

  f32x4 acc[4][4];
#pragma unroll
  for (int m = 0; m < 4; ++m)
#pragma unroll
    for (int n = 0; n < 4; ++n) acc[m][n] = (f32x4){0.f, 0.f, 0.f, 0.f};

  const int rsel = lane & 15;
  const int ksel = (lane >> 4) << 3;

  for (int k0 = 0; k0 < K; k0 += 64) {
#pragma unroll
    for (int i = 0; i < 4; ++i) {
      const short* asrc;
      if (AM == 1) asrc = ((k0 < HD) ? abase[i] : pbase[i]) + (k0 & (HD - 1)) + lc;
      else         asrc = abase[i] + k0 + lc;
      GLOAD16(asrc, &ldsA[(i * 32 + lr) * 64 + lc]);
      GLOAD16(bbase[i] + k0 + lc, &ldsB[(i * 32 + lr) * 64 + lc]);
    }
    __syncthreads();
#pragma unroll
    for (int kk = 0; kk < 64; kk += 32) {
      bf16x8 af[4], bg[4];
#pragma unroll
      for (int m = 0; m < 4; ++m)
        af[m] = *(const bf16x8*)&ldsA[(wr * 64 + m * 16 + rsel) * 64 + kk + ksel];
#pragma unroll
      for (int n = 0; n < 4; ++n)
        bg[n] = *(const bf16x8*)&ldsB[(wc * 64 + n * 16 + rsel) * 64 + kk + ksel];
#pragma unroll
      for (int m = 0; m < 4; ++m)
#pragma unroll
        for (int n = 0; n < 4; ++n)
          acc[m][n] = __builtin_amdgcn_mfma_f32_16x16x32_bf16(af[m], bg[n], acc[m][n], 0, 0, 0);
    }
    __syncthreads();
  }

  // C/D layout: col = lane&15, row = (lane>>4)*4 + reg
  const int row0 = bm + wr * 64 + ((lane >> 4) << 2);
  const int col0 = bn + wc * 64 + (lane & 15);
#pragma unroll
  for (int m = 0; m < 4; ++m) {
#pragma unroll
    for (int n = 0; n < 4; ++n) {
      const int col = col0 + n * 16;
      const float bv = (EPI == 0) ? 0.f : bias[col];
#pragma unroll
      for (int j = 0; j < 4; ++j) {
        const int row = row0 + m * 16 + j;
        const float v = acc[m][n][j] + bv;
        if (EPI == 0) {
          oF[(size_t)z * SEQ * N + (size_t)row * N + col] = v;
        } else if (EPI == 1) {
          oB[((size_t)z * CAP + row) * N + col] = f2bf(fmaxf(v, 0.f));
        } else if (EPI == 2) {
          if (row < NC) {
            const int t  = idx[row];
            const int lk = lkf[t];
            const float* cur = z ? vals : keys;
            const float prev = (lk >= 0) ? cur[(size_t)lk * HD + col] : 0.f;
            const float pred = prev + v;
            const float c  = cur[(size_t)t * HD + col];
            const float bl = blend[t];
            oF[((size_t)z * SEQ + t) * HD + col] = bl * c + (1.f - bl) * pred;
            oB[((size_t)z * CAP + row) * HD + col] = f2bf(c - pred);
          }
        } else {
          if (row < NC) {
            const int t  = idx[row];
            const float bl = blend[t];
            float* p = oF + ((size_t)z * SEQ + t) * HD + col;
            *p = *p + (1.f - bl) * fmaxf(v, 0.f);
          }
        }
      }
    }
  }
}

extern "C" void kernel_launch(void* const* d_in, const int* in_sizes, int n_in,
                              void* d_out, int out_size, void* d_ws, size_t ws_size,
                              hipStream_t stream) {
  const float* keys  = (const float*)d_in[0];
  const float* vals  = (const float*)d_in[1];
  const float* imp   = (const float*)d_in[2];
  const float* kmW1  = (const float*)d_in[3];
  const float* kmb1  = (const float*)d_in[4];
  const float* kmW2  = (const float*)d_in[5];
  const float* kmb2  = (const float*)d_in[6];
  const float* vmW1  = (const float*)d_in[7];
  const float* vmb1  = (const float*)d_in[8];
  const float* vmW2  = (const float*)d_in[9];
  const float* vmb2  = (const float*)d_in[10];
  const float* encW  = (const float*)d_in[11];
  const float* encb  = (const float*)d_in[12];
  const float* decW  = (const float*)d_in[13];
  const float* decb  = (const float*)d_in[14];
  const float* selW1 = (const float*)d_in[15];
  const float* selb1 = (const float*)d_in[16];
  const float* selW2 = (const float*)d_in[17];
  const float* selb2 = (const float*)d_in[18];
  const int*   fc    = (const int*)d_in[19];
  float* out = (float*)d_out;

  // ---- arena (<=113 MiB; lifetime-overlapped) ----
  const size_t MB = 1u << 20;
  char* ws = (char*)d_ws;
  short* kmW1t = (short*)(ws +  0 * MB);   // [2048][4096] 16M  dead after km1vm1
  short* vmW1t = (short*)(ws + 16 * MB);   // [2048][4096] 16M  dead after km1vm1
  short* rC    = (short*)(ws +  0 * MB);   // [2*CAP][2048] 24M born @km2vm2
  short* kmW2t = (short*)(ws + 32 * MB);   // [2048][2048] 8M   dead after km2vm2
  short* vmW2t = (short*)(ws + 40 * MB);   // [2048][2048] 8M   dead after km2vm2
  short* eC    = (short*)(ws + 32 * MB);   // [2*CAP][1024] 12M born @enc
  short* encT  = (short*)(ws + 48 * MB);   // [1024][2048] 4M
  short* decT  = (short*)(ws + 52 * MB);   // [2048][1024] 4M
  short* Ahi   = (short*)(ws + 56 * MB);   // [4096][2048] 16M  dead after km1vm1
  short* Vhi   = (short*)(ws + 72 * MB);   // [4096][2048] 16M  dead after km1vm1
  short* Alo   = (short*)(ws + 88 * MB);   // [4096][2048] 16M  dead after selector
  short* WhiT  = (short*)(ws + 104 * MB);  // [1024][2048] 4M   dead after selector
  short* WloT  = (short*)(ws + 108 * MB);  // [1024][2048] 4M   dead after selector
  short* hidC  = (short*)(ws + 88 * MB);   // [2*CAP][2048] 24M born @km1vm1
  char*  fl    = ws + 112 * MB;
  int*   iskf  = (int*)(fl);
  int*   lkf   = (int*)(fl + 16384);
  float* blend = (float*)(fl + 32768);
  int*   idx   = (int*)(fl + 49152);
  int*   ncp   = (int*)(fl + 65536);
  short* zrow  = (short*)(fl + 65536 + 256);   // 2048 bf16 zeros

  // selector partials h0,h1,h2 live in d_out [0,48MiB) until sel_logits
  float* h0 = (float*)d_out;
  float* h1 = h0 + (size_t)SEQ * CD;
  float* h2 = h1 + (size_t)SEQ * CD;

  dim3 tb(32, 8);
  transpose_cast<<<dim3(HD/32, 2*HD/32), tb, 0, stream>>>(kmW1, kmW1t, 2*HD, HD);
  transpose_cast<<<dim3(HD/32,   HD/32), tb, 0, stream>>>(kmW2, kmW2t,   HD, HD);
  transpose_cast<<<dim3(HD/32, 2*HD/32), tb, 0, stream>>>(vmW1, vmW1t, 2*HD, HD);
  transpose_cast<<<dim3(HD/32,   HD/32), tb, 0, stream>>>(vmW2, vmW2t,   HD, HD);
  transpose_cast<<<dim3(CD/32,   HD/32), tb, 0, stream>>>(encW, encT,    HD, CD);
  transpose_cast<<<dim3(HD/32,   CD/32), tb, 0, stream>>>(decW, decT,    CD, HD);
  transpose_hilo<<<dim3(CD/32,   HD/32), tb, 0, stream>>>(selW1, WhiT, WloT, HD, CD);
  build_hilo<<<dim3(HD/1024, SEQ), 256, 0, stream>>>(keys, vals, Ahi, Alo, Vhi);

  // selector: 3 z-slices (hi*Whi, lo*Whi, hi*Wlo), K=2048 each -> partials in d_out
  gemm_z<0,0><<<dim3(CD/128, SEQ/128, 3), 256, 0, stream>>>(
      Ahi, Alo, Ahi, WhiT, WhiT, WloT, nullptr, nullptr, CD, HD,
      h0, nullptr, nullptr, nullptr, nullptr, nullptr, nullptr, nullptr, nullptr);
  sel_logits<<<SEQ/4, 256, 0, stream>>>(h0, h1, h2, selb1, selW2, selb2, imp, fc, iskf, blend);
  kf_scan<<<1, 1024, 0, stream>>>(iskf, lkf, idx, ncp, zrow);
  copy_kf<<<dim3(HD/1024, SEQ), 256, 0, stream>>>(keys, vals, iskf, out);

  // km1+vm1 fused (gathered rows, K=4096: [cur|prev] panels) -> hidC
  gemm_z<1,1><<<dim3(HD/128, CAP/128, 2), 256, 0, stream>>>(
      Ahi, Vhi, nullptr, kmW1t, vmW1t, nullptr, kmb1, vmb1, HD, 2*HD,
      nullptr, hidC, idx, lkf, ncp, nullptr, nullptr, nullptr, zrow);
  // km2+vm2 fused -> blended pred into out (oF!), residuals rC   [FIX: oF was nullptr]
  gemm_z<2,2><<<dim3(HD/128, CAP/128, 2), 256, 0, stream>>>(
      hidC, hidC, nullptr, kmW2t, vmW2t, nullptr, kmb2, vmb2, HD, HD,
      out, rC, idx, lkf, ncp, blend, keys, vals, nullptr);
  // enc (shared weights, z = k/v half) -> eC
  gemm_z<1,2><<<dim3(CD/128, CAP/128, 2), 256, 0, stream>>>(
      rC, rC, nullptr, encT, encT, nullptr, encb, encb, CD, HD,
      nullptr, eC, idx, lkf, ncp, nullptr, nullptr, nullptr, nullptr);
  // dec -> out += (1-bl)*relu(.)
  gemm_z<3,2><<<dim3(HD/128, CAP/128, 2), 256, 0, stream>>>(
      eC, eC, nullptr, decT, decT, nullptr, decb, decb, HD, CD,
      out, nullptr, idx, lkf, ncp, blend, keys, vals, nullptr);
}